// Round 6
// baseline (1315.154 us; speedup 1.0000x reference)
//
#include <hip/hip_runtime.h>
#include <math.h>

// 2-layer LSTM (B=1024,T=512,F=64,H=128) + FC head.
// R11: R10 wave-specialized structure (1024 thr: waves 0-7 rec, 8-15 helper)
// with the LDS pipe + post-barrier burst attacked:
//  - pool/sb staging ELIMINATED: helpers load x / h1 directly from global in
//    MFMA A-layout (lane16=row, k=quad*8+j -> contiguous 16-32B/lane);
//    split2 in registers. 8x cross-wave redundancy lands in L1/L2, not LDS.
//  - helpers run TWO steps ahead: xacc(t+2) -> xbuf[3 slots]; rec waves
//    EARLY-READ slot (t+1) at the end of step t (written at t-1, visible
//    since the last barrier) -> post-barrier chain = hbuf reads only, and
//    LDS traffic spreads across the step instead of bursting.
//  - 3-slot rotation via one rotating byte-offset register.
// Numerics identical to R10 (same MFMA/accumulation order, same split2).
// Sync protocol identical (flag=2tp+1 at tp%4==3 after helper heavy-barrier
// drain; epilogue TT; consumer waits 15 / min(t+15,TT)).

#define BB 1024
#define TT 512
#define FF 64
#define HH 128
#define LOG2E 1.44269504088896340736f
#define TWOLOG2E 2.88539008177792681472f
#define XSLOT (512 * 20)   // dwords per xbuf slot

typedef __attribute__((ext_vector_type(8))) short     v8s;  // 8 x bf16
typedef __attribute__((ext_vector_type(8))) _Float16  v8h;  // 8 x fp16
typedef __attribute__((ext_vector_type(4))) float     v4f;

__device__ __forceinline__ short bf16r(float v) {  // RNE fp32->bf16
    unsigned u = __float_as_uint(v);
    return (short)((u + 0x7FFFu + ((u >> 16) & 1u)) >> 16);
}
__device__ __forceinline__ float bf16tof(short s) {
    return __uint_as_float(((unsigned)(unsigned short)s) << 16);
}
// rcp(1 + exp2(y)) : core of exp2-domain sigmoid/tanh.
__device__ __forceinline__ float rcp1p(float y) {
    return __builtin_amdgcn_rcpf(1.0f + __builtin_exp2f(y));
}
__device__ __forceinline__ void light_barrier() {
    asm volatile("s_waitcnt lgkmcnt(0)\n\ts_barrier" ::: "memory");
}
__device__ __forceinline__ void heavy_barrier() {
    asm volatile("s_waitcnt vmcnt(0) lgkmcnt(0)\n\ts_barrier" ::: "memory");
}
__device__ __forceinline__ void wait_flag_ge(int* f, int need) {
    for (int i = 0; i < 2000000; ++i) {
        int v = __hip_atomic_fetch_add(f, 0, __ATOMIC_ACQUIRE,
                                       __HIP_MEMORY_SCOPE_AGENT);
        if (v >= need) return;
        __builtin_amdgcn_s_sleep(4);
    }
}
// Truncation-based hi/lo bf16 split of two floats, packed into 2 u32.
__device__ __forceinline__ void split2(float a, float b,
                                       unsigned& hi, unsigned& lo) {
    unsigned ua = __float_as_uint(a), ub = __float_as_uint(b);
    hi = (ua >> 16) | (ub & 0xFFFF0000u);
    float ra = a - __uint_as_float(ua & 0xFFFF0000u);
    float rb = b - __uint_as_float(ub & 0xFFFF0000u);
    lo = (__float_as_uint(ra) >> 16) | (__float_as_uint(rb) & 0xFFFF0000u);
}
// Build split-bf16 MFMA A-frag (8 consecutive x elems) from 2 float4s.
__device__ __forceinline__ void mk_frag(const float4& a, const float4& b,
                                        v8s& hi, v8s& lo) {
    unsigned h0,l0,h1,l1,h2,l2,h3,l3;
    split2(a.x, a.y, h0, l0); split2(a.z, a.w, h1, l1);
    split2(b.x, b.y, h2, l2); split2(b.z, b.w, h3, l3);
    unsigned* H = (unsigned*)&hi; unsigned* L = (unsigned*)&lo;
    H[0]=h0; H[1]=h1; H[2]=h2; H[3]=h3;
    L[0]=l0; L[1]=l1; L[2]=l2; L[3]=l3;
}

// MFMA 16x16x32 layouts: A/B: m(n)=lane&15, k=(lane>>4)*8+j ; C/D: col=lane&15,
// row=(lane>>4)*4+r.

// ---- recurrence step (rec waves); early-reads next xacc from xbuf[sA] ----
#define REC_STEP(CUR, NXT, tv, STORE_HS)                                       \
  {                                                                            \
    v8h ah[4];                                                                 \
    _Pragma("unroll") for (int q = 0; q < 4; ++q)                              \
        ah[q] = *(const v8h*)&hbuf[CUR][lane16 * 136 + q * 32 + quad * 8];     \
    v4f g0 = xacc[0], g1 = xacc[1], g2 = xacc[2], g3 = xacc[3];                \
    _Pragma("unroll") for (int q = 0; q < 4; ++q) {                            \
      g0 = __builtin_amdgcn_mfma_f32_16x16x32_f16(ah[q], bh[0][q], g0, 0, 0, 0);\
      g1 = __builtin_amdgcn_mfma_f32_16x16x32_f16(ah[q], bh[1][q], g1, 0, 0, 0);\
      g2 = __builtin_amdgcn_mfma_f32_16x16x32_f16(ah[q], bh[2][q], g2, 0, 0, 0);\
      g3 = __builtin_amdgcn_mfma_f32_16x16x32_f16(ah[q], bh[3][q], g3, 0, 0, 0);\
    }                                                                          \
    _Pragma("unroll") for (int r = 0; r < 4; ++r) {                            \
      float ig = rcp1p(-g0[r]);                                                \
      float fg = rcp1p(-g1[r]);                                                \
      float gt = fmaf(-2.0f, rcp1p(g2[r]), 1.0f);                              \
      float og = rcp1p(-g3[r]);                                                \
      c[r] = fmaf(fg, c[r], ig * gt);                                          \
      float th = fmaf(-2.0f, rcp1p(TWOLOG2E * c[r]), 1.0f);                    \
      float h = og * th;                                                       \
      hbuf[NXT][(quad * 4 + r) * 136 + jh] = (_Float16)h;                      \
      if ((STORE_HS) && (tv) == TT - 1)                                        \
        hs[(b0 + quad * 4 + r) * HH + jh] = h;                                 \
    }                                                                          \
    _Pragma("unroll") for (int g = 0; g < 4; ++g)                              \
        xacc[g] = *(const v4f*)&xb[sA + g * 2560 + jh * 20 + quad * 4];        \
    sA = (sA == 2 * XSLOT) ? 0 : sA + XSLOT;                                   \
    light_barrier();                                                           \
  }

// ---- producer helper: h1c store of h(t-1); xacc(t+2) -> xbuf[sW]; prefetch --
#define PHELP_STEP(CUR, tv, HEAVY)                                             \
  {                                                                            \
    if ((tv) > 0) {                                                            \
      uint2 hv = *(const uint2*)&hbuf[CUR][hr_row * 136 + hr_col];             \
      *(uint2*)hcs = hv;                                                       \
      hcs += (long)BB * HH;                                                    \
    }                                                                          \
    v8s xh0, xl0, xh1, xl1;                                                    \
    mk_frag(pf0, pf1, xh0, xl0);                                               \
    mk_frag(pf2, pf3, xh1, xl1);                                               \
    {                                                                          \
      const float* p_ = xrow + (long)((tv) + 3 < TT ? (tv) + 3 : TT - 1) * FF; \
      pf0 = *(const float4*)p_;        pf1 = *(const float4*)(p_ + 4);         \
      pf2 = *(const float4*)(p_ + 32); pf3 = *(const float4*)(p_ + 36);        \
    }                                                                          \
    _Pragma("unroll") for (int g = 0; g < 4; ++g) {                            \
      v4f a = {bias[g], bias[g], bias[g], bias[g]};                            \
      a = __builtin_amdgcn_mfma_f32_16x16x32_bf16(xh0, bxh[g][0], a, 0, 0, 0); \
      a = __builtin_amdgcn_mfma_f32_16x16x32_bf16(xh0, bxl[g][0], a, 0, 0, 0); \
      a = __builtin_amdgcn_mfma_f32_16x16x32_bf16(xl0, bxh[g][0], a, 0, 0, 0); \
      a = __builtin_amdgcn_mfma_f32_16x16x32_bf16(xh1, bxh[g][1], a, 0, 0, 0); \
      a = __builtin_amdgcn_mfma_f32_16x16x32_bf16(xh1, bxl[g][1], a, 0, 0, 0); \
      a = __builtin_amdgcn_mfma_f32_16x16x32_bf16(xl1, bxh[g][1], a, 0, 0, 0); \
      *(v4f*)&xb[sW + g * 2560 + jh * 20 + quad * 4] = a;                      \
    }                                                                          \
    sW = (sW == 2 * XSLOT) ? 0 : sW + XSLOT;                                   \
    if (HEAVY) heavy_barrier(); else light_barrier();                          \
  }

// ---- consumer helper: a1acc(t+2) -> xbuf[sW] from prefetched h1; prefetch --
#define CHELP_STEP(tv)                                                         \
  {                                                                            \
    _Pragma("unroll") for (int g = 0; g < 4; ++g) {                            \
      v4f a = {bias[g], bias[g], bias[g], bias[g]};                            \
      _Pragma("unroll") for (int q = 0; q < 4; ++q)                            \
          a = __builtin_amdgcn_mfma_f32_16x16x32_f16(a1n[q], bi[g][q], a, 0, 0, 0);\
      *(v4f*)&xb[sW + g * 2560 + jh * 20 + quad * 4] = a;                      \
    }                                                                          \
    {                                                                          \
      const _Float16* p_ = hrow + (long)((tv)+3 < TT ? (tv)+3 : TT-1) * BB * HH;\
      _Pragma("unroll") for (int q = 0; q < 4; ++q)                            \
          a1n[q] = *(const v8h*)(p_ + 32 * q);                                 \
    }                                                                          \
    sW = (sW == 2 * XSLOT) ? 0 : sW + XSLOT;                                   \
    light_barrier();                                                           \
  }

__global__ __launch_bounds__(1024, 1) void fused_lstm_kernel(
    const float* __restrict__ x,
    const float* __restrict__ Wih0, const float* __restrict__ Whh0,
    const float* __restrict__ bih0, const float* __restrict__ bhh0,
    const float* __restrict__ Wih1, const float* __restrict__ Whh1,
    const float* __restrict__ bih1, const float* __restrict__ bhh1,
    _Float16* __restrict__ h1c, float* __restrict__ hs, int* __restrict__ flags)
{
    const int tid = threadIdx.x;
    const bool isrec = tid < 512;       // waves 0-7: recurrence
    const int l = tid & 63;
    const int lane16 = l & 15;
    const int quad = l >> 4;
    const int jh = 16 * ((tid >> 6) & 7) + lane16;
    const int stid = tid & 511;
    const int hr_row = stid >> 5;       // coop-store row 0..15
    const int hr_col = (stid & 31) * 4; // 0..124 (x4 halves)

    __shared__ __align__(16) _Float16 hbuf[2][16 * 136];   //   8704 B
    __shared__ __align__(16) float    xb[3 * XSLOT];       // 122880 B

    if (blockIdx.x < 64) {
        // ================= LAYER 0 (producer) =================
        const int tile = blockIdx.x;
        const long b0 = (long)tile * 16;
        int* flagp = &flags[tile];

        if (isrec) {
            v8h bh[4][4];
#pragma unroll
            for (int g = 0; g < 4; ++g) {
                const int col = g * 128 + jh;
                const float sg = (g == 2) ? TWOLOG2E : LOG2E;
#pragma unroll
                for (int q = 0; q < 4; ++q) {
                    const float* p = &Whh0[(long)col * HH + q * 32 + quad * 8];
                    float4 u0 = *(const float4*)p;
                    float4 u1 = *(const float4*)(p + 4);
                    v8h t;
                    t[0]=(_Float16)(u0.x*sg); t[1]=(_Float16)(u0.y*sg);
                    t[2]=(_Float16)(u0.z*sg); t[3]=(_Float16)(u0.w*sg);
                    t[4]=(_Float16)(u1.x*sg); t[5]=(_Float16)(u1.y*sg);
                    t[6]=(_Float16)(u1.z*sg); t[7]=(_Float16)(u1.w*sg);
                    bh[g][q] = t;
                }
            }
            for (int i = tid; i < 16 * 136; i += 512) hbuf[0][i] = (_Float16)0.0f;
            float c[4] = {0.f, 0.f, 0.f, 0.f};
            __syncthreads();            // helper wrote xbuf slots 0,1

            v4f xacc[4];
#pragma unroll
            for (int g = 0; g < 4; ++g)
                xacc[g] = *(const v4f*)&xb[0 + g * 2560 + jh * 20 + quad * 4];
            int sA = XSLOT;             // step t early-reads slot (t+1)%3

            for (int tp = 0; tp < TT / 2; ++tp) {
                REC_STEP(0, 1, 2 * tp, 0);
                REC_STEP(1, 0, 2 * tp + 1, 0);
                if ((tp & 3) == 3 && tid == 0)
                    __hip_atomic_store(flagp, 2 * tp + 1, __ATOMIC_RELEASE,
                                       __HIP_MEMORY_SCOPE_AGENT);
            }
            light_barrier();            // helper stored h(TT-1), drained
            if (tid == 0)
                __hip_atomic_store(flagp, TT, __ATOMIC_RELEASE,
                                   __HIP_MEMORY_SCOPE_AGENT);
        } else {
            float bias[4];
            v8s bxh[4][2], bxl[4][2];
#pragma unroll
            for (int g = 0; g < 4; ++g) {
                const int col = g * 128 + jh;
                const float sg = (g == 2) ? TWOLOG2E : LOG2E;
                bias[g] = (bih0[col] + bhh0[col]) * sg;
#pragma unroll
                for (int q = 0; q < 2; ++q) {
                    const float* p = &Wih0[(long)col * FF + q * 32 + quad * 8];
                    float4 u0 = *(const float4*)p;
                    float4 u1 = *(const float4*)(p + 4);
                    float vv[8] = {u0.x,u0.y,u0.z,u0.w,u1.x,u1.y,u1.z,u1.w};
                    v8s hi, lo;
#pragma unroll
                    for (int e = 0; e < 8; ++e) {
                        float vs = vv[e] * sg;
                        short hbits = bf16r(vs);
                        hi[e] = hbits;
                        lo[e] = bf16r(vs - bf16tof(hbits));
                    }
                    bxh[g][q] = hi; bxl[g][q] = lo;
                }
            }
            // direct global x loads in MFMA A-layout
            const float* xrow = x + (b0 + lane16) * (long)TT * FF + quad * 8;
            float4 pf0, pf1, pf2, pf3;
            {
                // xacc(0) -> slot 0
                float4 a0 = *(const float4*)xrow;
                float4 a1 = *(const float4*)(xrow + 4);
                float4 a2 = *(const float4*)(xrow + 32);
                float4 a3 = *(const float4*)(xrow + 36);
                v8s xh0, xl0, xh1, xl1;
                mk_frag(a0, a1, xh0, xl0); mk_frag(a2, a3, xh1, xl1);
#pragma unroll
                for (int g = 0; g < 4; ++g) {
                    v4f a = {bias[g], bias[g], bias[g], bias[g]};
                    a = __builtin_amdgcn_mfma_f32_16x16x32_bf16(xh0, bxh[g][0], a, 0, 0, 0);
                    a = __builtin_amdgcn_mfma_f32_16x16x32_bf16(xh0, bxl[g][0], a, 0, 0, 0);
                    a = __builtin_amdgcn_mfma_f32_16x16x32_bf16(xl0, bxh[g][0], a, 0, 0, 0);
                    a = __builtin_amdgcn_mfma_f32_16x16x32_bf16(xh1, bxh[g][1], a, 0, 0, 0);
                    a = __builtin_amdgcn_mfma_f32_16x16x32_bf16(xh1, bxl[g][1], a, 0, 0, 0);
                    a = __builtin_amdgcn_mfma_f32_16x16x32_bf16(xl1, bxh[g][1], a, 0, 0, 0);
                    *(v4f*)&xb[0 + g * 2560 + jh * 20 + quad * 4] = a;
                }
                // xacc(1) -> slot 1
                const float* p1 = xrow + FF;
                a0 = *(const float4*)p1;        a1 = *(const float4*)(p1 + 4);
                a2 = *(const float4*)(p1 + 32); a3 = *(const float4*)(p1 + 36);
                mk_frag(a0, a1, xh0, xl0); mk_frag(a2, a3, xh1, xl1);
#pragma unroll
                for (int g = 0; g < 4; ++g) {
                    v4f a = {bias[g], bias[g], bias[g], bias[g]};
                    a = __builtin_amdgcn_mfma_f32_16x16x32_bf16(xh0, bxh[g][0], a, 0, 0, 0);
                    a = __builtin_amdgcn_mfma_f32_16x16x32_bf16(xh0, bxl[g][0], a, 0, 0, 0);
                    a = __builtin_amdgcn_mfma_f32_16x16x32_bf16(xl0, bxh[g][0], a, 0, 0, 0);
                    a = __builtin_amdgcn_mfma_f32_16x16x32_bf16(xh1, bxh[g][1], a, 0, 0, 0);
                    a = __builtin_amdgcn_mfma_f32_16x16x32_bf16(xh1, bxl[g][1], a, 0, 0, 0);
                    a = __builtin_amdgcn_mfma_f32_16x16x32_bf16(xl1, bxh[g][1], a, 0, 0, 0);
                    *(v4f*)&xb[XSLOT + g * 2560 + jh * 20 + quad * 4] = a;
                }
                // prefetch x(2)
                const float* p2 = xrow + 2 * FF;
                pf0 = *(const float4*)p2;        pf1 = *(const float4*)(p2 + 4);
                pf2 = *(const float4*)(p2 + 32); pf3 = *(const float4*)(p2 + 36);
            }
            __syncthreads();
            int sW = 2 * XSLOT;         // step t writes slot (t+2)%3
            _Float16* hcs = h1c + (b0 + hr_row) * HH + hr_col;

            for (int tp = 0; tp < TT / 2; ++tp) {
                PHELP_STEP(0, 2 * tp, 0);
                PHELP_STEP(1, 2 * tp + 1, ((tp & 3) == 3));
            }
            // epilogue: store h(TT-1) (lives in hbuf[0])
            {
                uint2 hv = *(const uint2*)&hbuf[0][hr_row * 136 + hr_col];
                *(uint2*)hcs = hv;
            }
            heavy_barrier();
        }
    } else {
        // ================= LAYER 1 (consumer) =================
        const int tile = blockIdx.x - 64;
        const long b0 = (long)tile * 16;
        int* flagp = &flags[tile];

        if (isrec) {
            v8h bh[4][4];
#pragma unroll
            for (int g = 0; g < 4; ++g) {
                const int col = g * 128 + jh;
                const float sg = (g == 2) ? TWOLOG2E : LOG2E;
#pragma unroll
                for (int q = 0; q < 4; ++q) {
                    const float* ph = &Whh1[(long)col * HH + q * 32 + quad * 8];
                    float4 v0 = *(const float4*)ph;
                    float4 v1 = *(const float4*)(ph + 4);
                    v8h s;
                    s[0]=(_Float16)(v0.x*sg); s[1]=(_Float16)(v0.y*sg);
                    s[2]=(_Float16)(v0.z*sg); s[3]=(_Float16)(v0.w*sg);
                    s[4]=(_Float16)(v1.x*sg); s[5]=(_Float16)(v1.y*sg);
                    s[6]=(_Float16)(v1.z*sg); s[7]=(_Float16)(v1.w*sg);
                    bh[g][q] = s;
                }
            }
            for (int i = tid; i < 16 * 136; i += 512) hbuf[0][i] = (_Float16)0.0f;
            float c[4] = {0.f, 0.f, 0.f, 0.f};
            if (tid == 0) wait_flag_ge(flagp, 15);
            __syncthreads();            // releases helper global reads
            light_barrier();            // helper wrote xbuf slots 0,1

            v4f xacc[4];
#pragma unroll
            for (int g = 0; g < 4; ++g)
                xacc[g] = *(const v4f*)&xb[0 + g * 2560 + jh * 20 + quad * 4];
            int sA = XSLOT;

            for (int tp = 0; tp < TT / 2; ++tp) {
                if ((tp & 3) == 0 && tp > 0) {
                    if (tid == 0)
                        wait_flag_ge(flagp, (2 * tp + 15 < TT) ? 2 * tp + 15 : TT);
                    light_barrier();
                }
                REC_STEP(0, 1, 2 * tp, 1);
                REC_STEP(1, 0, 2 * tp + 1, 1);
            }
        } else {
            float bias[4];
            v8h bi[4][4];
#pragma unroll
            for (int g = 0; g < 4; ++g) {
                const int col = g * 128 + jh;
                const float sg = (g == 2) ? TWOLOG2E : LOG2E;
                bias[g] = (bih1[col] + bhh1[col]) * sg;
#pragma unroll
                for (int q = 0; q < 4; ++q) {
                    const float* pi = &Wih1[(long)col * HH + q * 32 + quad * 8];
                    float4 u0 = *(const float4*)pi;
                    float4 u1 = *(const float4*)(pi + 4);
                    v8h t;
                    t[0]=(_Float16)(u0.x*sg); t[1]=(_Float16)(u0.y*sg);
                    t[2]=(_Float16)(u0.z*sg); t[3]=(_Float16)(u0.w*sg);
                    t[4]=(_Float16)(u1.x*sg); t[5]=(_Float16)(u1.y*sg);
                    t[6]=(_Float16)(u1.z*sg); t[7]=(_Float16)(u1.w*sg);
                    bi[g][q] = t;
                }
            }
            const _Float16* hrow = h1c + (b0 + lane16) * HH + quad * 8;
            __syncthreads();            // rec tid0 completed wait_flag_ge(15)

            v8h a1n[4];
            {
                v8h t0[4];
                // a1acc(0) -> slot 0
#pragma unroll
                for (int q = 0; q < 4; ++q)
                    t0[q] = *(const v8h*)(hrow + 32 * q);
#pragma unroll
                for (int g = 0; g < 4; ++g) {
                    v4f a = {bias[g], bias[g], bias[g], bias[g]};
#pragma unroll
                    for (int q = 0; q < 4; ++q)
                        a = __builtin_amdgcn_mfma_f32_16x16x32_f16(t0[q], bi[g][q], a, 0, 0, 0);
                    *(v4f*)&xb[0 + g * 2560 + jh * 20 + quad * 4] = a;
                }
                // a1acc(1) -> slot 1
#pragma unroll
                for (int q = 0; q < 4; ++q)
                    t0[q] = *(const v8h*)(hrow + (long)BB * HH + 32 * q);
#pragma unroll
                for (int g = 0; g < 4; ++g) {
                    v4f a = {bias[g], bias[g], bias[g], bias[g]};
#pragma unroll
                    for (int q = 0; q < 4; ++q)
                        a = __builtin_amdgcn_mfma_f32_16x16x32_f16(t0[q], bi[g][q], a, 0, 0, 0);
                    *(v4f*)&xb[XSLOT + g * 2560 + jh * 20 + quad * 4] = a;
                }
                // prefetch h1(2)
#pragma unroll
                for (int q = 0; q < 4; ++q)
                    a1n[q] = *(const v8h*)(hrow + 2L * BB * HH + 32 * q);
            }
            light_barrier();
            int sW = 2 * XSLOT;

            for (int tp = 0; tp < TT / 2; ++tp) {
                if ((tp & 3) == 0 && tp > 0) light_barrier();
                CHELP_STEP(2 * tp);
                CHELP_STEP(2 * tp + 1);
            }
        }
    }
}

// ---------------- FC head: out = relu(h @ fc1^T + b1) @ fc2^T + b2 ----------
__global__ __launch_bounds__(64) void head_kernel(
    const float* __restrict__ h, const float* __restrict__ w1,
    const float* __restrict__ b1, const float* __restrict__ w2,
    const float* __restrict__ b2, float* __restrict__ out)
{
    const int b = blockIdx.x;
    const int n = threadIdx.x;
    float acc = b1[n];
#pragma unroll
    for (int k = 0; k < HH; ++k)
        acc = fmaf(w1[n * HH + k], h[b * HH + k], acc);
    float v = fmaxf(acc, 0.0f) * w2[n];
#pragma unroll
    for (int off = 32; off > 0; off >>= 1)
        v += __shfl_down(v, off);
    if (n == 0) out[b] = v + b2[0];
}

extern "C" void kernel_launch(void* const* d_in, const int* in_sizes, int n_in,
                              void* d_out, int out_size, void* d_ws, size_t ws_size,
                              hipStream_t stream)
{
    const float* x    = (const float*)d_in[0];
    const float* Wih0 = (const float*)d_in[1];
    const float* Whh0 = (const float*)d_in[2];
    const float* bih0 = (const float*)d_in[3];
    const float* bhh0 = (const float*)d_in[4];
    const float* Wih1 = (const float*)d_in[5];
    const float* Whh1 = (const float*)d_in[6];
    const float* bih1 = (const float*)d_in[7];
    const float* bhh1 = (const float*)d_in[8];
    const float* w1   = (const float*)d_in[9];
    const float* b1   = (const float*)d_in[10];
    const float* w2   = (const float*)d_in[11];
    const float* b2   = (const float*)d_in[12];
    float* out = (float*)d_out;

    char* ws = (char*)d_ws;
    _Float16* h1c = (_Float16*)ws;                              // 134 MB, [t][B][H]
    float* hs  = (float*)(ws + (size_t)BB * TT * HH * sizeof(_Float16));
    int* flags = (int*)(ws + (size_t)BB * TT * HH * sizeof(_Float16)
                           + (size_t)BB * HH * sizeof(float));

    hipMemsetAsync(flags, 0, 64 * sizeof(int), stream);

    fused_lstm_kernel<<<128, 1024, 0, stream>>>(
        x, Wih0, Whh0, bih0, bhh0, Wih1, Whh1, bih1, bhh1, h1c, hs, flags);
    head_kernel<<<BB, 64, 0, stream>>>(hs, w1, b1, w2, b2, out);
}

// Round 7
// 1275.269 us; speedup vs baseline: 1.0313x; 1.0313x over previous
//
#include <hip/hip_runtime.h>
#include <math.h>

// 2-layer LSTM (B=1024,T=512,F=64,H=128) + FC head.
// R12: recover R11's bank-conflict regression. R11 root cause: rec waves'
// xbuf EARLY-READ (end of step) landed in the same cycle window as helper
// xbuf writes; slots are bank-aligned (stride % 32 == 0) -> sustained
// cross-wave read/write conflicts (2.5e7 -> 1.089e8). R12 restores R10's
// 2-slot xbuf layout AND timing (rec reads xbuf[CUR] immediately
// post-barrier; helpers write xbuf[NXT] mid-step) while KEEPING R11's good
// changes:
//  - pool/sb LDS staging eliminated: helper A-frags loaded directly from
//    global in MFMA A-layout (lane16=row, k=quad*8+j), split2 in registers.
//  - double-buffered prefetch register sets (pfA/pfB, a1A/a1B): loads issue
//    a full step ahead of use, and BEFORE the h1c store in the vmcnt queue
//    (no store-drain on the load wait).
// Numerics bit-identical to R10 (same split2 / MFMA / accumulation order).
// Sync protocol identical (flag=2tp+1 at tp%4==3 after helper heavy-barrier
// drain; epilogue TT; consumer waits 15 / min(2tp+15,TT)).

#define BB 1024
#define TT 512
#define FF 64
#define HH 128
#define LOG2E 1.44269504088896340736f
#define TWOLOG2E 2.88539008177792681472f

typedef __attribute__((ext_vector_type(8))) short     v8s;  // 8 x bf16
typedef __attribute__((ext_vector_type(8))) _Float16  v8h;  // 8 x fp16
typedef __attribute__((ext_vector_type(4))) float     v4f;

__device__ __forceinline__ short bf16r(float v) {  // RNE fp32->bf16
    unsigned u = __float_as_uint(v);
    return (short)((u + 0x7FFFu + ((u >> 16) & 1u)) >> 16);
}
__device__ __forceinline__ float bf16tof(short s) {
    return __uint_as_float(((unsigned)(unsigned short)s) << 16);
}
// rcp(1 + exp2(y)) : core of exp2-domain sigmoid/tanh.
__device__ __forceinline__ float rcp1p(float y) {
    return __builtin_amdgcn_rcpf(1.0f + __builtin_exp2f(y));
}
__device__ __forceinline__ void light_barrier() {
    asm volatile("s_waitcnt lgkmcnt(0)\n\ts_barrier" ::: "memory");
}
__device__ __forceinline__ void heavy_barrier() {
    asm volatile("s_waitcnt vmcnt(0) lgkmcnt(0)\n\ts_barrier" ::: "memory");
}
__device__ __forceinline__ void wait_flag_ge(int* f, int need) {
    for (int i = 0; i < 2000000; ++i) {
        int v = __hip_atomic_fetch_add(f, 0, __ATOMIC_ACQUIRE,
                                       __HIP_MEMORY_SCOPE_AGENT);
        if (v >= need) return;
        __builtin_amdgcn_s_sleep(4);
    }
}
// Truncation-based hi/lo bf16 split of two floats, packed into 2 u32.
__device__ __forceinline__ void split2(float a, float b,
                                       unsigned& hi, unsigned& lo) {
    unsigned ua = __float_as_uint(a), ub = __float_as_uint(b);
    hi = (ua >> 16) | (ub & 0xFFFF0000u);
    float ra = a - __uint_as_float(ua & 0xFFFF0000u);
    float rb = b - __uint_as_float(ub & 0xFFFF0000u);
    lo = (__float_as_uint(ra) >> 16) | (__float_as_uint(rb) & 0xFFFF0000u);
}
// Build split-bf16 MFMA A-frag (8 consecutive x elems) from 2 float4s.
__device__ __forceinline__ void mk_frag(const float4& a, const float4& b,
                                        v8s& hi, v8s& lo) {
    unsigned h0,l0,h1,l1,h2,l2,h3,l3;
    split2(a.x, a.y, h0, l0); split2(a.z, a.w, h1, l1);
    split2(b.x, b.y, h2, l2); split2(b.z, b.w, h3, l3);
    unsigned* H = (unsigned*)&hi; unsigned* L = (unsigned*)&lo;
    H[0]=h0; H[1]=h1; H[2]=h2; H[3]=h3;
    L[0]=l0; L[1]=l1; L[2]=l2; L[3]=l3;
}

// MFMA 16x16x32 layouts: A/B: m(n)=lane&15, k=(lane>>4)*8+j ; C/D: col=lane&15,
// row=(lane>>4)*4+r.

// ---- recurrence step (rec waves): xbuf[CUR] read immediately post-barrier --
#define REC_STEP(CUR, NXT, tv, STORE_HS)                                       \
  {                                                                            \
    v4f g0 = *(const v4f*)&xbuf[CUR][0 * 2560 + jh * 20 + quad * 4];           \
    v4f g1 = *(const v4f*)&xbuf[CUR][1 * 2560 + jh * 20 + quad * 4];           \
    v4f g2 = *(const v4f*)&xbuf[CUR][2 * 2560 + jh * 20 + quad * 4];           \
    v4f g3 = *(const v4f*)&xbuf[CUR][3 * 2560 + jh * 20 + quad * 4];           \
    v8h ah[4];                                                                 \
    _Pragma("unroll") for (int q = 0; q < 4; ++q)                              \
        ah[q] = *(const v8h*)&hbuf[CUR][lane16 * 136 + q * 32 + quad * 8];     \
    _Pragma("unroll") for (int q = 0; q < 4; ++q) {                            \
      g0 = __builtin_amdgcn_mfma_f32_16x16x32_f16(ah[q], bh[0][q], g0, 0, 0, 0);\
      g1 = __builtin_amdgcn_mfma_f32_16x16x32_f16(ah[q], bh[1][q], g1, 0, 0, 0);\
      g2 = __builtin_amdgcn_mfma_f32_16x16x32_f16(ah[q], bh[2][q], g2, 0, 0, 0);\
      g3 = __builtin_amdgcn_mfma_f32_16x16x32_f16(ah[q], bh[3][q], g3, 0, 0, 0);\
    }                                                                          \
    _Pragma("unroll") for (int r = 0; r < 4; ++r) {                            \
      float ig = rcp1p(-g0[r]);                                                \
      float fg = rcp1p(-g1[r]);                                                \
      float gt = fmaf(-2.0f, rcp1p(g2[r]), 1.0f);                              \
      float og = rcp1p(-g3[r]);                                                \
      c[r] = fmaf(fg, c[r], ig * gt);                                          \
      float th = fmaf(-2.0f, rcp1p(TWOLOG2E * c[r]), 1.0f);                    \
      float h = og * th;                                                       \
      hbuf[NXT][(quad * 4 + r) * 136 + jh] = (_Float16)h;                      \
      if ((STORE_HS) && (tv) == TT - 1)                                        \
        hs[(b0 + quad * 4 + r) * HH + jh] = h;                                 \
    }                                                                          \
  }

// ---- producer helper step: prefetch x(t+2)->PFLD, h1c store h(t-1),
//      xacc(t+1)=bias+Wih0*x(t+1) from PFUSE -> xbuf[NXT] ----
#define PHELP_STEP(CUR, NXT, PFUSE, PFLD, tv, HEAVY)                           \
  {                                                                            \
    {                                                                          \
      const float* p_ = xrow + (long)((tv) + 2 < TT ? (tv) + 2 : TT - 1) * FF; \
      PFLD##0 = *(const float4*)p_;        PFLD##1 = *(const float4*)(p_ + 4); \
      PFLD##2 = *(const float4*)(p_ + 32); PFLD##3 = *(const float4*)(p_ + 36);\
    }                                                                          \
    if ((tv) > 0) {                                                            \
      uint2 hv = *(const uint2*)&hbuf[CUR][hr_row * 136 + hr_col];             \
      *(uint2*)hcs = hv;                                                       \
      hcs += (long)BB * HH;                                                    \
    }                                                                          \
    v8s xh0, xl0, xh1, xl1;                                                    \
    mk_frag(PFUSE##0, PFUSE##1, xh0, xl0);                                     \
    mk_frag(PFUSE##2, PFUSE##3, xh1, xl1);                                     \
    _Pragma("unroll") for (int g = 0; g < 4; ++g) {                            \
      v4f a = {bias[g], bias[g], bias[g], bias[g]};                            \
      a = __builtin_amdgcn_mfma_f32_16x16x32_bf16(xh0, bxh[g][0], a, 0, 0, 0); \
      a = __builtin_amdgcn_mfma_f32_16x16x32_bf16(xh0, bxl[g][0], a, 0, 0, 0); \
      a = __builtin_amdgcn_mfma_f32_16x16x32_bf16(xl0, bxh[g][0], a, 0, 0, 0); \
      a = __builtin_amdgcn_mfma_f32_16x16x32_bf16(xh1, bxh[g][1], a, 0, 0, 0); \
      a = __builtin_amdgcn_mfma_f32_16x16x32_bf16(xh1, bxl[g][1], a, 0, 0, 0); \
      a = __builtin_amdgcn_mfma_f32_16x16x32_bf16(xl1, bxh[g][1], a, 0, 0, 0); \
      *(v4f*)&xbuf[NXT][g * 2560 + jh * 20 + quad * 4] = a;                    \
    }                                                                          \
    if (HEAVY) heavy_barrier(); else light_barrier();                          \
  }

// ---- consumer helper step: prefetch h1(t+2)->ALD, a1acc(t+1) from AUSE ----
#define CHELP_STEP(NXT, AUSE, ALD, tv)                                         \
  {                                                                            \
    {                                                                          \
      const _Float16* p_ = hrow + (long)((tv)+2 < TT ? (tv)+2 : TT-1) * BB * HH;\
      _Pragma("unroll") for (int q = 0; q < 4; ++q)                            \
          ALD[q] = *(const v8h*)(p_ + 32 * q);                                 \
    }                                                                          \
    _Pragma("unroll") for (int g = 0; g < 4; ++g) {                            \
      v4f a = {bias[g], bias[g], bias[g], bias[g]};                            \
      _Pragma("unroll") for (int q = 0; q < 4; ++q)                            \
          a = __builtin_amdgcn_mfma_f32_16x16x32_f16(AUSE[q], bi[g][q], a, 0, 0, 0);\
      *(v4f*)&xbuf[NXT][g * 2560 + jh * 20 + quad * 4] = a;                    \
    }                                                                          \
    light_barrier();                                                           \
  }

__global__ __launch_bounds__(1024, 1) void fused_lstm_kernel(
    const float* __restrict__ x,
    const float* __restrict__ Wih0, const float* __restrict__ Whh0,
    const float* __restrict__ bih0, const float* __restrict__ bhh0,
    const float* __restrict__ Wih1, const float* __restrict__ Whh1,
    const float* __restrict__ bih1, const float* __restrict__ bhh1,
    _Float16* __restrict__ h1c, float* __restrict__ hs, int* __restrict__ flags)
{
    const int tid = threadIdx.x;
    const bool isrec = tid < 512;       // waves 0-7: recurrence
    const int l = tid & 63;
    const int lane16 = l & 15;
    const int quad = l >> 4;
    const int jh = 16 * ((tid >> 6) & 7) + lane16;
    const int stid = tid & 511;
    const int hr_row = stid >> 5;       // coop-store row 0..15
    const int hr_col = (stid & 31) * 4; // 0..124 (x4 halves)

    __shared__ __align__(16) _Float16 hbuf[2][16 * 136];   //  8704 B
    __shared__ __align__(16) float    xbuf[2][512 * 20];   // 81920 B

    if (blockIdx.x < 64) {
        // ================= LAYER 0 (producer) =================
        const int tile = blockIdx.x;
        const long b0 = (long)tile * 16;
        int* flagp = &flags[tile];

        if (isrec) {
            v8h bh[4][4];
#pragma unroll
            for (int g = 0; g < 4; ++g) {
                const int col = g * 128 + jh;
                const float sg = (g == 2) ? TWOLOG2E : LOG2E;
#pragma unroll
                for (int q = 0; q < 4; ++q) {
                    const float* p = &Whh0[(long)col * HH + q * 32 + quad * 8];
                    float4 u0 = *(const float4*)p;
                    float4 u1 = *(const float4*)(p + 4);
                    v8h t;
                    t[0]=(_Float16)(u0.x*sg); t[1]=(_Float16)(u0.y*sg);
                    t[2]=(_Float16)(u0.z*sg); t[3]=(_Float16)(u0.w*sg);
                    t[4]=(_Float16)(u1.x*sg); t[5]=(_Float16)(u1.y*sg);
                    t[6]=(_Float16)(u1.z*sg); t[7]=(_Float16)(u1.w*sg);
                    bh[g][q] = t;
                }
            }
            for (int i = stid; i < 16 * 136; i += 512) hbuf[0][i] = (_Float16)0.0f;
            float c[4] = {0.f, 0.f, 0.f, 0.f};
            __syncthreads();            // A: helper wrote xbuf[0]

            for (int tp = 0; tp < TT / 2; ++tp) {
                REC_STEP(0, 1, 2 * tp, 0);
                light_barrier();
                REC_STEP(1, 0, 2 * tp + 1, 0);
                light_barrier();
                if ((tp & 3) == 3 && tid == 0)
                    __hip_atomic_store(flagp, 2 * tp + 1, __ATOMIC_RELEASE,
                                       __HIP_MEMORY_SCOPE_AGENT);
            }
            light_barrier();            // pairs: helper epilogue heavy drain
            if (tid == 0)
                __hip_atomic_store(flagp, TT, __ATOMIC_RELEASE,
                                   __HIP_MEMORY_SCOPE_AGENT);
        } else {
            float bias[4];
            v8s bxh[4][2], bxl[4][2];
#pragma unroll
            for (int g = 0; g < 4; ++g) {
                const int col = g * 128 + jh;
                const float sg = (g == 2) ? TWOLOG2E : LOG2E;
                bias[g] = (bih0[col] + bhh0[col]) * sg;
#pragma unroll
                for (int q = 0; q < 2; ++q) {
                    const float* p = &Wih0[(long)col * FF + q * 32 + quad * 8];
                    float4 u0 = *(const float4*)p;
                    float4 u1 = *(const float4*)(p + 4);
                    float vv[8] = {u0.x,u0.y,u0.z,u0.w,u1.x,u1.y,u1.z,u1.w};
                    v8s hi, lo;
#pragma unroll
                    for (int e = 0; e < 8; ++e) {
                        float vs = vv[e] * sg;
                        short hbits = bf16r(vs);
                        hi[e] = hbits;
                        lo[e] = bf16r(vs - bf16tof(hbits));
                    }
                    bxh[g][q] = hi; bxl[g][q] = lo;
                }
            }
            // direct global x loads in MFMA A-layout
            const float* xrow = x + (b0 + lane16) * (long)TT * FF + quad * 8;
            float4 pfA0, pfA1, pfA2, pfA3, pfB0, pfB1, pfB2, pfB3;
            {
                // xacc(0) -> xbuf[0]
                float4 a0 = *(const float4*)xrow;
                float4 a1 = *(const float4*)(xrow + 4);
                float4 a2 = *(const float4*)(xrow + 32);
                float4 a3 = *(const float4*)(xrow + 36);
                v8s xh0, xl0, xh1, xl1;
                mk_frag(a0, a1, xh0, xl0); mk_frag(a2, a3, xh1, xl1);
#pragma unroll
                for (int g = 0; g < 4; ++g) {
                    v4f a = {bias[g], bias[g], bias[g], bias[g]};
                    a = __builtin_amdgcn_mfma_f32_16x16x32_bf16(xh0, bxh[g][0], a, 0, 0, 0);
                    a = __builtin_amdgcn_mfma_f32_16x16x32_bf16(xh0, bxl[g][0], a, 0, 0, 0);
                    a = __builtin_amdgcn_mfma_f32_16x16x32_bf16(xl0, bxh[g][0], a, 0, 0, 0);
                    a = __builtin_amdgcn_mfma_f32_16x16x32_bf16(xh1, bxh[g][1], a, 0, 0, 0);
                    a = __builtin_amdgcn_mfma_f32_16x16x32_bf16(xh1, bxl[g][1], a, 0, 0, 0);
                    a = __builtin_amdgcn_mfma_f32_16x16x32_bf16(xl1, bxh[g][1], a, 0, 0, 0);
                    *(v4f*)&xbuf[0][g * 2560 + jh * 20 + quad * 4] = a;
                }
                // prefetch x(1) into pfA (used at step t=0)
                const float* p1 = xrow + FF;
                pfA0 = *(const float4*)p1;        pfA1 = *(const float4*)(p1 + 4);
                pfA2 = *(const float4*)(p1 + 32); pfA3 = *(const float4*)(p1 + 36);
            }
            __syncthreads();            // A
            _Float16* hcs = h1c + (b0 + hr_row) * HH + hr_col;

            for (int tp = 0; tp < TT / 2; ++tp) {
                PHELP_STEP(0, 1, pfA, pfB, 2 * tp, 0);
                PHELP_STEP(1, 0, pfB, pfA, 2 * tp + 1, ((tp & 3) == 3));
            }
            // epilogue: store h(TT-1) (lives in hbuf[0])
            {
                uint2 hv = *(const uint2*)&hbuf[0][hr_row * 136 + hr_col];
                *(uint2*)hcs = hv;
            }
            heavy_barrier();
        }
    } else {
        // ================= LAYER 1 (consumer) =================
        const int tile = blockIdx.x - 64;
        const long b0 = (long)tile * 16;
        int* flagp = &flags[tile];

        if (isrec) {
            v8h bh[4][4];
#pragma unroll
            for (int g = 0; g < 4; ++g) {
                const int col = g * 128 + jh;
                const float sg = (g == 2) ? TWOLOG2E : LOG2E;
#pragma unroll
                for (int q = 0; q < 4; ++q) {
                    const float* ph = &Whh1[(long)col * HH + q * 32 + quad * 8];
                    float4 v0 = *(const float4*)ph;
                    float4 v1 = *(const float4*)(ph + 4);
                    v8h s;
                    s[0]=(_Float16)(v0.x*sg); s[1]=(_Float16)(v0.y*sg);
                    s[2]=(_Float16)(v0.z*sg); s[3]=(_Float16)(v0.w*sg);
                    s[4]=(_Float16)(v1.x*sg); s[5]=(_Float16)(v1.y*sg);
                    s[6]=(_Float16)(v1.z*sg); s[7]=(_Float16)(v1.w*sg);
                    bh[g][q] = s;
                }
            }
            for (int i = stid; i < 16 * 136; i += 512) hbuf[0][i] = (_Float16)0.0f;
            float c[4] = {0.f, 0.f, 0.f, 0.f};
            if (tid == 0) wait_flag_ge(flagp, 15);
            __syncthreads();            // A: releases helper h1c reads
            light_barrier();            // B: helper wrote xbuf[0]

            for (int tp = 0; tp < TT / 2; ++tp) {
                if ((tp & 3) == 0 && tp > 0) {
                    if (tid == 0)
                        wait_flag_ge(flagp, (2 * tp + 15 < TT) ? 2 * tp + 15 : TT);
                    light_barrier();
                }
                REC_STEP(0, 1, 2 * tp, 1);
                light_barrier();
                REC_STEP(1, 0, 2 * tp + 1, 1);
                light_barrier();
            }
        } else {
            float bias[4];
            v8h bi[4][4];
#pragma unroll
            for (int g = 0; g < 4; ++g) {
                const int col = g * 128 + jh;
                const float sg = (g == 2) ? TWOLOG2E : LOG2E;
                bias[g] = (bih1[col] + bhh1[col]) * sg;
#pragma unroll
                for (int q = 0; q < 4; ++q) {
                    const float* pi = &Wih1[(long)col * HH + q * 32 + quad * 8];
                    float4 u0 = *(const float4*)pi;
                    float4 u1 = *(const float4*)(pi + 4);
                    v8h t;
                    t[0]=(_Float16)(u0.x*sg); t[1]=(_Float16)(u0.y*sg);
                    t[2]=(_Float16)(u0.z*sg); t[3]=(_Float16)(u0.w*sg);
                    t[4]=(_Float16)(u1.x*sg); t[5]=(_Float16)(u1.y*sg);
                    t[6]=(_Float16)(u1.z*sg); t[7]=(_Float16)(u1.w*sg);
                    bi[g][q] = t;
                }
            }
            const _Float16* hrow = h1c + (b0 + lane16) * HH + quad * 8;
            __syncthreads();            // A: rec tid0 completed flag wait

            v8h a1A[4], a1B[4];
            {
                v8h t0[4];
                // a1acc(0) -> xbuf[0]
#pragma unroll
                for (int q = 0; q < 4; ++q)
                    t0[q] = *(const v8h*)(hrow + 32 * q);
#pragma unroll
                for (int g = 0; g < 4; ++g) {
                    v4f a = {bias[g], bias[g], bias[g], bias[g]};
#pragma unroll
                    for (int q = 0; q < 4; ++q)
                        a = __builtin_amdgcn_mfma_f32_16x16x32_f16(t0[q], bi[g][q], a, 0, 0, 0);
                    *(v4f*)&xbuf[0][g * 2560 + jh * 20 + quad * 4] = a;
                }
                // prefetch h1(1) into a1A (used at step t=0)
#pragma unroll
                for (int q = 0; q < 4; ++q)
                    a1A[q] = *(const v8h*)(hrow + (long)BB * HH + 32 * q);
            }
            light_barrier();            // B

            for (int tp = 0; tp < TT / 2; ++tp) {
                if ((tp & 3) == 0 && tp > 0) light_barrier();
                CHELP_STEP(1, a1A, a1B, 2 * tp);
                CHELP_STEP(0, a1B, a1A, 2 * tp + 1);
            }
        }
    }
}

// ---------------- FC head: out = relu(h @ fc1^T + b1) @ fc2^T + b2 ----------
__global__ __launch_bounds__(64) void head_kernel(
    const float* __restrict__ h, const float* __restrict__ w1,
    const float* __restrict__ b1, const float* __restrict__ w2,
    const float* __restrict__ b2, float* __restrict__ out)
{
    const int b = blockIdx.x;
    const int n = threadIdx.x;
    float acc = b1[n];
#pragma unroll
    for (int k = 0; k < HH; ++k)
        acc = fmaf(w1[n * HH + k], h[b * HH + k], acc);
    float v = fmaxf(acc, 0.0f) * w2[n];
#pragma unroll
    for (int off = 32; off > 0; off >>= 1)
        v += __shfl_down(v, off);
    if (n == 0) out[b] = v + b2[0];
}

extern "C" void kernel_launch(void* const* d_in, const int* in_sizes, int n_in,
                              void* d_out, int out_size, void* d_ws, size_t ws_size,
                              hipStream_t stream)
{
    const float* x    = (const float*)d_in[0];
    const float* Wih0 = (const float*)d_in[1];
    const float* Whh0 = (const float*)d_in[2];
    const float* bih0 = (const float*)d_in[3];
    const float* bhh0 = (const float*)d_in[4];
    const float* Wih1 = (const float*)d_in[5];
    const float* Whh1 = (const float*)d_in[6];
    const float* bih1 = (const float*)d_in[7];
    const float* bhh1 = (const float*)d_in[8];
    const float* w1   = (const float*)d_in[9];
    const float* b1   = (const float*)d_in[10];
    const float* w2   = (const float*)d_in[11];
    const float* b2   = (const float*)d_in[12];
    float* out = (float*)d_out;

    char* ws = (char*)d_ws;
    _Float16* h1c = (_Float16*)ws;                              // 134 MB, [t][B][H]
    float* hs  = (float*)(ws + (size_t)BB * TT * HH * sizeof(_Float16));
    int* flags = (int*)(ws + (size_t)BB * TT * HH * sizeof(_Float16)
                           + (size_t)BB * HH * sizeof(float));

    hipMemsetAsync(flags, 0, 64 * sizeof(int), stream);

    fused_lstm_kernel<<<128, 1024, 0, stream>>>(
        x, Wih0, Whh0, bih0, bhh0, Wih1, Whh1, bih1, bhh1, h1c, hs, flags);
    head_kernel<<<BB, 64, 0, stream>>>(hs, w1, b1, w2, b2, out);
}